// Round 1
// baseline (132.364 us; speedup 1.0000x reference)
//
#include <hip/hip_runtime.h>

#define BB   16384
#define NF   24
#define CARDN 10000
#define DD   16
#define NI   276      // 24*23/2
#define H1N  128
#define H2N  64

// ---------------------------------------------------------------------------
// Kernel A: per-(sample, pair) gather + 16-dim dot product.
// pair p -> (i, j), i<j. Reads E[i, x_i, j, :] and E[j, x_j, i, :] (64B each,
// contiguous, float4-vectorized). Each ordered slice is read exactly once
// across the whole kernel, so gather traffic is minimal by construction.
// ---------------------------------------------------------------------------
__global__ __launch_bounds__(256) void pairs_kernel(
    const int* __restrict__ x, const float* __restrict__ E,
    float* __restrict__ pairs)
{
    int tid = blockIdx.x * 256 + threadIdx.x;   // < BB*NI == 4,521,984
    int b = tid / NI;
    int p = tid - b * NI;

    // decode upper-triangular pair index (row-major, k=1)
    int i = 0, rem = p, cnt = NF - 1;
    while (rem >= cnt) { rem -= cnt; --cnt; ++i; }
    int j = i + 1 + rem;

    int xi = x[b * NF + i];
    int xj = x[b * NF + j];

    const float4* a = (const float4*)(E + ((size_t)i * CARDN + xi) * (NF * DD) + j * DD);
    const float4* c = (const float4*)(E + ((size_t)j * CARDN + xj) * (NF * DD) + i * DD);
    float4 a0 = a[0], a1 = a[1], a2 = a[2], a3 = a[3];
    float4 c0 = c[0], c1 = c[1], c2 = c[2], c3 = c[3];

    float s =
        a0.x*c0.x + a0.y*c0.y + a0.z*c0.z + a0.w*c0.w +
        a1.x*c1.x + a1.y*c1.y + a1.z*c1.z + a1.w*c1.w +
        a2.x*c2.x + a2.y*c2.y + a2.z*c2.z + a2.w*c2.w +
        a3.x*c3.x + a3.y*c3.y + a3.z*c3.z + a3.w*c3.w;

    pairs[tid] = s;
}

// ---------------------------------------------------------------------------
// Kernel B: fused MLP (276 -> 128 -> 64 -> 1) + linear term, 32 samples/block.
// pairs tile staged in LDS; W1/W2/W3 stream from L2 (tiny, fully resident).
// All math in f32 (no fp32 MFMA on CDNA4; compute here is ~10us, negligible
// next to the gather kernel).
// ---------------------------------------------------------------------------
__global__ __launch_bounds__(256) void mlp_kernel(
    const float* __restrict__ pairs, const int* __restrict__ x,
    const float* __restrict__ Wlin, const float* __restrict__ blin,
    const float* __restrict__ W1, const float* __restrict__ b1,
    const float* __restrict__ W2, const float* __restrict__ b2,
    const float* __restrict__ W3, const float* __restrict__ b3,
    float* __restrict__ out)
{
    const int BT = 32;
    __shared__ float pairs_s[BT * NI];   // 8832 f; later overlaid by h2 [32][65]
    __shared__ float h1_s[BT * H1N];     // 4096 f
    __shared__ float lin_s[BT];

    int tid = threadIdx.x;
    int b0 = blockIdx.x * BT;

    // --- stage pairs tile (contiguous, float4) ---
    {
        const float4* src = (const float4*)(pairs + (size_t)b0 * NI);
        float4* dst = (float4*)pairs_s;
        for (int idx = tid; idx < BT * NI / 4; idx += 256) dst[idx] = src[idx];
    }
    // --- linear term (+ blin + b3 folded in) ---
    if (tid < BT) {
        float l = blin[0] + b3[0];
        const int* xr = x + (size_t)(b0 + tid) * NF;
        #pragma unroll
        for (int i = 0; i < NF; ++i) l += Wlin[i * CARDN + xr[i]];
        lin_s[tid] = l;
    }
    __syncthreads();

    // --- GEMM1: h1[s][c] = relu(pairs[s][:] . W1[:][c] + b1[c]) ---
    {
        int c4 = tid & 31;     // c0 = c4*4 (128 cols)
        int sg = tid >> 5;     // 0..7 ; s = sg*4+si
        float acc[4][4] = {};
        for (int p = 0; p < NI; ++p) {
            float4 w = *(const float4*)(W1 + p * H1N + c4 * 4);
            #pragma unroll
            for (int si = 0; si < 4; ++si) {
                float pr = pairs_s[(sg * 4 + si) * NI + p];
                acc[si][0] = fmaf(pr, w.x, acc[si][0]);
                acc[si][1] = fmaf(pr, w.y, acc[si][1]);
                acc[si][2] = fmaf(pr, w.z, acc[si][2]);
                acc[si][3] = fmaf(pr, w.w, acc[si][3]);
            }
        }
        float4 bb = *(const float4*)(b1 + c4 * 4);
        #pragma unroll
        for (int si = 0; si < 4; ++si) {
            float4 h;
            h.x = fmaxf(acc[si][0] + bb.x, 0.f);
            h.y = fmaxf(acc[si][1] + bb.y, 0.f);
            h.z = fmaxf(acc[si][2] + bb.z, 0.f);
            h.w = fmaxf(acc[si][3] + bb.w, 0.f);
            *(float4*)(h1_s + (sg * 4 + si) * H1N + c4 * 4) = h;
        }
    }
    __syncthreads();

    // --- GEMM2: h2[s][c] = relu(h1[s][:] . W2[:][c] + b2[c]) ---
    // h2 overlays pairs_s region, padded stride 65 to dodge bank conflicts.
    float* h2_s = pairs_s;
    {
        int c16 = tid & 15;    // c0 = c16*4 (64 cols)
        int sg2 = tid >> 4;    // 0..15 ; s = sg2*2+si
        float acc[2][4] = {};
        for (int p = 0; p < H1N; ++p) {
            float4 w = *(const float4*)(W2 + p * H2N + c16 * 4);
            #pragma unroll
            for (int si = 0; si < 2; ++si) {
                float pr = h1_s[(sg2 * 2 + si) * H1N + p];
                acc[si][0] = fmaf(pr, w.x, acc[si][0]);
                acc[si][1] = fmaf(pr, w.y, acc[si][1]);
                acc[si][2] = fmaf(pr, w.z, acc[si][2]);
                acc[si][3] = fmaf(pr, w.w, acc[si][3]);
            }
        }
        float4 bb = *(const float4*)(b2 + c16 * 4);
        #pragma unroll
        for (int si = 0; si < 2; ++si) {
            int s = sg2 * 2 + si;
            float v0 = fmaxf(acc[si][0] + bb.x, 0.f);
            float v1 = fmaxf(acc[si][1] + bb.y, 0.f);
            float v2 = fmaxf(acc[si][2] + bb.z, 0.f);
            float v3 = fmaxf(acc[si][3] + bb.w, 0.f);
            int base = s * 65 + c16 * 4;
            h2_s[base + 0] = v0;
            h2_s[base + 1] = v1;
            h2_s[base + 2] = v2;
            h2_s[base + 3] = v3;
        }
    }
    __syncthreads();

    // --- GEMM3 + linear: out[s] = h2[s][:] . W3 + (lin + blin + b3) ---
    {
        int s  = tid >> 3;     // 0..31
        int ko = tid & 7;      // 8 lanes per sample
        float r = 0.f;
        #pragma unroll
        for (int kk = 0; kk < 8; ++kk) {
            int k = ko * 8 + kk;
            r = fmaf(h2_s[s * 65 + k], W3[k], r);
        }
        r += __shfl_xor(r, 1);
        r += __shfl_xor(r, 2);
        r += __shfl_xor(r, 4);
        if (ko == 0) out[b0 + s] = r + lin_s[s];
    }
}

extern "C" void kernel_launch(void* const* d_in, const int* in_sizes, int n_in,
                              void* d_out, int out_size, void* d_ws, size_t ws_size,
                              hipStream_t stream) {
    const int*   x    = (const int*)  d_in[0];
    const float* E    = (const float*)d_in[1];
    const float* Wlin = (const float*)d_in[2];
    const float* blin = (const float*)d_in[3];
    const float* W1   = (const float*)d_in[4];
    const float* b1   = (const float*)d_in[5];
    const float* W2   = (const float*)d_in[6];
    const float* b2   = (const float*)d_in[7];
    const float* W3   = (const float*)d_in[8];
    const float* b3   = (const float*)d_in[9];
    float* out   = (float*)d_out;
    float* pairs = (float*)d_ws;   // BB*NI floats = 18.1 MB

    pairs_kernel<<<(BB * NI) / 256, 256, 0, stream>>>(x, E, pairs);
    mlp_kernel<<<BB / 32, 256, 0, stream>>>(pairs, x, Wlin, blin,
                                            W1, b1, W2, b2, W3, b3, out);
}